// Round 9
// baseline (349.100 us; speedup 1.0000x reference)
//
#include <hip/hip_runtime.h>

#define N_NODES 20000
#define N_EDGES 640000
#define OBS 64
#define HDIM 256
#define MSGD 128
#define ADIM 16
#define Q_OFF 0
#define HN_OFF (N_NODES * ADIM)   // 320000

typedef __bf16 bf16x8 __attribute__((ext_vector_type(8)));
typedef float  f32x4  __attribute__((ext_vector_type(4)));

__device__ __forceinline__ unsigned short f2bf(float f) {
    union { float f; unsigned int i; } v; v.f = f;
    unsigned int i = v.i;
    return (unsigned short)((i + 0x7fffu + ((i >> 16) & 1u)) >> 16);
}
__device__ __forceinline__ float bf2f(unsigned short u) {
    union { unsigned int i; float f; } v; v.i = ((unsigned int)u) << 16; return v.f;
}
__device__ __forceinline__ bf16x8 ld8(const unsigned short* p) {
    bf16x8 r;
    __builtin_memcpy(&r, __builtin_assume_aligned(p, 16), 16);
    return r;
}
__device__ __forceinline__ f32x4 mfma16(bf16x8 a, bf16x8 b, f32x4 c) {
    return __builtin_amdgcn_mfma_f32_16x16x32_bf16(a, b, c, 0, 0, 0);
}
__device__ __forceinline__ float sigmoidf_(float x) { return 1.0f / (1.0f + __expf(-x)); }
__device__ __forceinline__ float tanhf_(float x) { return 2.0f / (1.0f + __expf(-2.0f * x)) - 1.0f; }

// fragment-packed layout: element (row,k) of a K-major matrix, Kc=K/32:
__device__ __forceinline__ int packIdx(int row, int k, int Kc) {
    return ((row >> 4) * Kc + (k >> 5)) * 512 + (((k >> 3) & 3) * 16 + (row & 15)) * 8 + (k & 7);
}
__device__ __forceinline__ int packIdxEp(int tile, int rlow, int t, int lr, int Kc) {
    return (tile * Kc + (t >> 1)) * 512 + (((t & 1) * 2 + (lr >> 3)) * 16 + rlow) * 8 + (lr & 7);
}

// ---------------- ws layout (bytes) ----------------
#define WS_W0P    0u
#define WS_W1P    32768u
#define WS_WMP    163840u
#define WS_WGP    294912u
#define WS_WOP    1277952u
#define WS_FEATP  1286144u
#define WS_HBP    3846144u
#define WS_X0P    14086144u
#define WS_XP     24326144u
#define WS_MN     34566144u
#define WS_CP     39686144u
#define WS_HNP    44806144u
#define WS_DEG    55046144u
#define WS_OFF    55126144u
#define WS_CUR    55206144u
#define WS_BUCKET 55286144u
#define WS_HBROW  57846144u   // row-major 20000 x 256 bf16 (end 68086144)

#define GATE_STRIDE 163840

// fused setup: feat/h -> bf16 (packed + row-major h), weight packing, dst histogram.
__global__ __launch_bounds__(256) void setup_kernel(
    const float* __restrict__ feat, const float* __restrict__ h,
    const float* __restrict__ w0, const float* __restrict__ w1, const float* __restrict__ wm,
    const float* __restrict__ wih, const float* __restrict__ whh, const float* __restrict__ wo,
    const int* __restrict__ dst,
    unsigned short* __restrict__ featp, unsigned short* __restrict__ hbp,
    unsigned short* __restrict__ hbrow,
    unsigned short* __restrict__ w0p, unsigned short* __restrict__ w1p,
    unsigned short* __restrict__ wmp, unsigned short* __restrict__ wgp,
    unsigned short* __restrict__ wop, int* __restrict__ deg)
{
    int tid = blockIdx.x * 256 + threadIdx.x;
    int np = gridDim.x * 256;
    for (int ch = tid; ch < N_NODES * OBS / 8; ch += np) {
        int row = ch >> 3, k = (ch & 7) * 8;
        const float4* p = (const float4*)(feat + row * OBS + k);
        float4 a = p[0], b = p[1];
        union { unsigned short u[8]; uint4 v; } r;
        r.u[0]=f2bf(a.x); r.u[1]=f2bf(a.y); r.u[2]=f2bf(a.z); r.u[3]=f2bf(a.w);
        r.u[4]=f2bf(b.x); r.u[5]=f2bf(b.y); r.u[6]=f2bf(b.z); r.u[7]=f2bf(b.w);
        *(uint4*)(featp + packIdx(row, k, 2)) = r.v;
    }
    for (int ch = tid; ch < N_NODES * HDIM / 8; ch += np) {
        int row = ch >> 5, k = (ch & 31) * 8;
        const float4* p = (const float4*)(h + row * HDIM + k);
        float4 a = p[0], b = p[1];
        union { unsigned short u[8]; uint4 v; } r;
        r.u[0]=f2bf(a.x); r.u[1]=f2bf(a.y); r.u[2]=f2bf(a.z); r.u[3]=f2bf(a.w);
        r.u[4]=f2bf(b.x); r.u[5]=f2bf(b.y); r.u[6]=f2bf(b.z); r.u[7]=f2bf(b.w);
        *(uint4*)(hbp + packIdx(row, k, 8)) = r.v;
        *(uint4*)(hbrow + row * HDIM + k) = r.v;
    }
    for (int i = tid; i < 64 * 256; i += np)  { int k = i >> 8, n = i & 255; w0p[packIdx(n, k, 2)]  = f2bf(w0[i]); }
    for (int i = tid; i < 256 * 256; i += np) { int k = i >> 8, n = i & 255; w1p[packIdx(n, k, 8)]  = f2bf(w1[i]); }
    for (int i = tid; i < 512 * 128; i += np) { int k = i >> 7, n = i & 127; wmp[packIdx(n, k, 16)] = f2bf(wm[i]); }
    for (int i = tid; i < 384 * 768; i += np) {
        int k = i / 768, c3 = i % 768;
        wgp[(c3 >> 8) * GATE_STRIDE + packIdx(c3 & 255, k, 20)] = f2bf(wih[i]);
    }
    for (int i = tid; i < 256 * 768; i += np) {
        int k = i / 768, c3 = i % 768;
        wgp[(c3 >> 8) * GATE_STRIDE + packIdx(c3 & 255, 384 + k, 20)] = f2bf(whh[i]);
    }
    for (int i = tid; i < 256 * 16; i += np)  { int k = i >> 4, n = i & 15; wop[packIdx(n, k, 8)] = f2bf(wo[i]); }
    for (int i = tid; i < N_EDGES; i += np) atomicAdd(&deg[dst[i]], 1);
}

__global__ __launch_bounds__(1024) void scan_kernel(const int* __restrict__ deg,
                                                    int* __restrict__ off, int* __restrict__ cur) {
    __shared__ int part[1024];
    const int t = threadIdx.x;
    const int base = t * 20;
    int s = 0;
    #pragma unroll
    for (int i = 0; i < 20; ++i) { int idx = base + i; if (idx < N_NODES) s += deg[idx]; }
    part[t] = s;
    __syncthreads();
    int acc = s;
    for (int d = 1; d < 1024; d <<= 1) {
        int v = (t >= d) ? part[t - d] : 0;
        __syncthreads();
        acc += v; part[t] = acc;
        __syncthreads();
    }
    int run = acc - s;
    for (int i = 0; i < 20; ++i) {
        int idx = base + i;
        if (idx < N_NODES) { off[idx] = run; cur[idx] = run; run += deg[idx]; }
    }
}

__global__ __launch_bounds__(256) void scatter_idx(const int* __restrict__ src, const int* __restrict__ dst,
                                                   int* __restrict__ cur, int* __restrict__ bucket) {
    int i = blockIdx.x * 256 + threadIdx.x;
    if (i < N_EDGES) {
        int d = dst[i];
        int pos = atomicAdd(&cur[d], 1);
        bucket[pos] = src[i];
    }
}

// enc0: X0 = relu(feat @ W0 + b0). 1252 blocks.
__global__ __launch_bounds__(256) void enc0_kernel(
    const unsigned short* __restrict__ featp, const unsigned short* __restrict__ w0p,
    const float* __restrict__ b0, unsigned short* __restrict__ X0p)
{
    const int w = blockIdx.x * 4 + (threadIdx.x >> 6);
    const int lane = threadIdx.x & 63, lr = lane & 15, lq = lane >> 4;
    const int m64 = w >> 4, t = w & 15;
    int tA[4]; bool val[4];
    #pragma unroll
    for (int mf = 0; mf < 4; ++mf) { int tl = m64 * 4 + mf; val[mf] = tl < 1250; tA[mf] = val[mf] ? tl : 1249; }
    f32x4 acc[4] = {{0,0,0,0},{0,0,0,0},{0,0,0,0},{0,0,0,0}};
    for (int c = 0; c < 2; ++c) {
        bf16x8 b = ld8(w0p + (t * 2 + c) * 512 + lane * 8);
        #pragma unroll
        for (int mf = 0; mf < 4; ++mf) {
            bf16x8 a = ld8(featp + (tA[mf] * 2 + c) * 512 + lane * 8);
            acc[mf] = mfma16(a, b, acc[mf]);
        }
    }
    float bias = b0[t * 16 + lr];
    #pragma unroll
    for (int mf = 0; mf < 4; ++mf) if (val[mf])
        #pragma unroll
        for (int r = 0; r < 4; ++r)
            X0p[packIdxEp(tA[mf], lq * 4 + r, t, lr, 8)] = f2bf(fmaxf(acc[mf][r] + bias, 0.f));
}

// enc1: X = relu(X0 @ W1 + b1). t-shared block, B staged in 8 KB LDS. grid 79*16.
__global__ __launch_bounds__(256) void enc1_kernel(
    const unsigned short* __restrict__ X0p, const unsigned short* __restrict__ w1p,
    const float* __restrict__ b1, unsigned short* __restrict__ Xp)
{
    const int t  = blockIdx.x & 15;
    const int mg = blockIdx.x >> 4;
    const int lane = threadIdx.x & 63, lr = lane & 15, lq = lane >> 4;
    int m64 = mg * 4 + (threadIdx.x >> 6); if (m64 > 312) m64 = 312;
    int tA[4]; bool val[4];
    #pragma unroll
    for (int mf = 0; mf < 4; ++mf) { int tl = m64 * 4 + mf; val[mf] = tl < 1250; tA[mf] = val[mf] ? tl : 1249; }

    __shared__ __align__(16) unsigned short wl[8][512];   // 8 KB
    for (int i = threadIdx.x; i < 512; i += 256)
        ((uint4*)wl)[i] = ((const uint4*)(w1p + t * 8 * 512))[i];
    __syncthreads();

    f32x4 acc[4] = {{0,0,0,0},{0,0,0,0},{0,0,0,0},{0,0,0,0}};
    for (int c = 0; c < 8; ++c) {
        bf16x8 b = ld8(&wl[c][lane * 8]);
        #pragma unroll
        for (int mf = 0; mf < 4; ++mf) {
            bf16x8 a = ld8(X0p + (tA[mf] * 8 + c) * 512 + lane * 8);
            acc[mf] = mfma16(a, b, acc[mf]);
        }
    }
    float bias = b1[t * 16 + lr];
    #pragma unroll
    for (int mf = 0; mf < 4; ++mf) if (val[mf])
        #pragma unroll
        for (int r = 0; r < 4; ++r)
            Xp[packIdxEp(tA[mf], lq * 4 + r, t, lr, 8)] = f2bf(fmaxf(acc[mf][r] + bias, 0.f));
}

// msg: Mnode = X @ Wx + h @ Wh + mb -> row-major. t-shared, 16 KB LDS. grid 79*8.
__global__ __launch_bounds__(256) void msg_kernel(
    const unsigned short* __restrict__ Xp, const unsigned short* __restrict__ hbp,
    const unsigned short* __restrict__ wmp, const float* __restrict__ mb,
    unsigned short* __restrict__ Mn)
{
    const int t  = blockIdx.x & 7;
    const int mg = blockIdx.x >> 3;
    const int lane = threadIdx.x & 63, lr = lane & 15, lq = lane >> 4;
    int m64 = mg * 4 + (threadIdx.x >> 6); if (m64 > 312) m64 = 312;
    const int col = t * 16 + lr;
    int tA[4]; bool val[4];
    #pragma unroll
    for (int mf = 0; mf < 4; ++mf) { int tl = m64 * 4 + mf; val[mf] = tl < 1250; tA[mf] = val[mf] ? tl : 1249; }

    __shared__ __align__(16) unsigned short wl[16][512];  // 16 KB
    for (int i = threadIdx.x; i < 1024; i += 256)
        ((uint4*)wl)[i] = ((const uint4*)(wmp + t * 16 * 512))[i];
    __syncthreads();

    f32x4 acc[4] = {{0,0,0,0},{0,0,0,0},{0,0,0,0},{0,0,0,0}};
    for (int c = 0; c < 8; ++c) {            // X part
        bf16x8 b = ld8(&wl[c][lane * 8]);
        #pragma unroll
        for (int mf = 0; mf < 4; ++mf) {
            bf16x8 a = ld8(Xp + (tA[mf] * 8 + c) * 512 + lane * 8);
            acc[mf] = mfma16(a, b, acc[mf]);
        }
    }
    for (int c = 0; c < 8; ++c) {            // h part
        bf16x8 b = ld8(&wl[8 + c][lane * 8]);
        #pragma unroll
        for (int mf = 0; mf < 4; ++mf) {
            bf16x8 a = ld8(hbp + (tA[mf] * 8 + c) * 512 + lane * 8);
            acc[mf] = mfma16(a, b, acc[mf]);
        }
    }
    float bias = mb[col];
    #pragma unroll
    for (int mf = 0; mf < 4; ++mf) if (val[mf])
        #pragma unroll
        for (int r = 0; r < 4; ++r) {
            int row = m64 * 64 + mf * 16 + lq * 4 + r;
            Mn[row * MSGD + col] = f2bf(acc[mf][r] + bias);
        }
}

// one wave per node: gather Mn rows, mean, write packed C row.
__global__ __launch_bounds__(256) void aggregate_kernel(
    const int* __restrict__ off, const int* __restrict__ deg,
    const int* __restrict__ bucket, const unsigned short* __restrict__ Mn,
    unsigned short* __restrict__ Cp)
{
    const int wave = threadIdx.x >> 6;
    const int lane = threadIdx.x & 63;
    const int node = blockIdx.x * 4 + wave;
    if (node >= N_NODES) return;
    const int o = off[node], dg = deg[node];
    float s0 = 0.f, s1 = 0.f;
    const unsigned int* mn = (const unsigned int*)Mn;
    int j = 0;
    for (; j + 4 <= dg; j += 4) {
        int i0 = bucket[o + j], i1 = bucket[o + j + 1], i2 = bucket[o + j + 2], i3 = bucket[o + j + 3];
        unsigned int p0 = mn[i0 * 64 + lane], p1 = mn[i1 * 64 + lane];
        unsigned int p2 = mn[i2 * 64 + lane], p3 = mn[i3 * 64 + lane];
        s0 += bf2f((unsigned short)(p0 & 0xffffu)) + bf2f((unsigned short)(p1 & 0xffffu))
            + bf2f((unsigned short)(p2 & 0xffffu)) + bf2f((unsigned short)(p3 & 0xffffu));
        s1 += bf2f((unsigned short)(p0 >> 16)) + bf2f((unsigned short)(p1 >> 16))
            + bf2f((unsigned short)(p2 >> 16)) + bf2f((unsigned short)(p3 >> 16));
    }
    for (; j < dg; ++j) {
        int sidx = bucket[o + j];
        unsigned int pk = mn[sidx * 64 + lane];
        s0 += bf2f((unsigned short)(pk & 0xffffu));
        s1 += bf2f((unsigned short)(pk >> 16));
    }
    float invc = 1.0f / fmaxf((float)dg, 1.0f);
    unsigned int outpk = ((unsigned int)f2bf(s1 * invc) << 16) | (unsigned int)f2bf(s0 * invc);
    *(unsigned int*)(Cp + packIdx(node, 2 * lane, 4)) = outpk;
}

// GRU gates + h_new. t-shared block; weight slice staged in LDS in two 30 KB
// phases. Per gate, tile t = ushorts [t*10240, t*10240+10240); phase 1 stages
// chunks 0..9 (+0..5120), phase 2 chunks 10..19 (+5120..10240). grid 79*16.
__global__ __launch_bounds__(256) void gru_kernel(
    const unsigned short* __restrict__ Xp, const unsigned short* __restrict__ Cp,
    const unsigned short* __restrict__ hbp, const unsigned short* __restrict__ hbrow,
    const unsigned short* __restrict__ wgp,
    const float* __restrict__ bih, const float* __restrict__ bhh,
    unsigned short* __restrict__ Hnp, float* __restrict__ out)
{
    const int t  = blockIdx.x & 15;
    const int mg = blockIdx.x >> 4;
    const int lane = threadIdx.x & 63, lr = lane & 15, lq = lane >> 4;
    int m64 = mg * 4 + (threadIdx.x >> 6); if (m64 > 312) m64 = 312;
    const int col = t * 16 + lr;
    int tA[4]; bool val[4];
    #pragma unroll
    for (int mf = 0; mf < 4; ++mf) { int tl = m64 * 4 + mf; val[mf] = tl < 1250; tA[mf] = val[mf] ? tl : 1249; }

    __shared__ __align__(16) unsigned short wlds[3][10][512];  // 30 KB (phased)

    f32x4 ar[4]  = {{0,0,0,0},{0,0,0,0},{0,0,0,0},{0,0,0,0}};
    f32x4 az[4]  = {{0,0,0,0},{0,0,0,0},{0,0,0,0},{0,0,0,0}};
    f32x4 ani[4] = {{0,0,0,0},{0,0,0,0},{0,0,0,0},{0,0,0,0}};
    f32x4 anh[4] = {{0,0,0,0},{0,0,0,0},{0,0,0,0},{0,0,0,0}};

    // ---- phase 1: stage weight chunks 0..9 of all 3 gates ----
    for (int i = threadIdx.x; i < 1920; i += 256) {
        int g = i / 640, o = i % 640;
        ((uint4*)wlds)[i] = ((const uint4*)(wgp + g * GATE_STRIDE + t * 10240))[o];
    }
    __syncthreads();
    for (int c = 0; c < 8; ++c) {        // X part (weight chunks 0..7)
        bf16x8 br = ld8(&wlds[0][c][lane * 8]);
        bf16x8 bz = ld8(&wlds[1][c][lane * 8]);
        bf16x8 bn = ld8(&wlds[2][c][lane * 8]);
        #pragma unroll
        for (int mf = 0; mf < 4; ++mf) {
            bf16x8 a = ld8(Xp + (tA[mf] * 8 + c) * 512 + lane * 8);
            ar[mf]  = mfma16(a, br, ar[mf]);
            az[mf]  = mfma16(a, bz, az[mf]);
            ani[mf] = mfma16(a, bn, ani[mf]);
        }
    }
    for (int c = 0; c < 2; ++c) {        // C chunks 0..1 (weight chunks 8..9)
        bf16x8 br = ld8(&wlds[0][8 + c][lane * 8]);
        bf16x8 bz = ld8(&wlds[1][8 + c][lane * 8]);
        bf16x8 bn = ld8(&wlds[2][8 + c][lane * 8]);
        #pragma unroll
        for (int mf = 0; mf < 4; ++mf) {
            bf16x8 a = ld8(Cp + (tA[mf] * 4 + c) * 512 + lane * 8);
            ar[mf]  = mfma16(a, br, ar[mf]);
            az[mf]  = mfma16(a, bz, az[mf]);
            ani[mf] = mfma16(a, bn, ani[mf]);
        }
    }
    __syncthreads();
    // ---- phase 2: stage weight chunks 10..19 (offset +5120 ushorts = 10 chunks) ----
    for (int i = threadIdx.x; i < 1920; i += 256) {
        int g = i / 640, o = i % 640;
        ((uint4*)wlds)[i] = ((const uint4*)(wgp + g * GATE_STRIDE + t * 10240 + 5120))[o];
    }
    __syncthreads();
    for (int c = 2; c < 4; ++c) {        // C chunks 2..3 (weight chunks 10..11 -> slots 0..1)
        bf16x8 br = ld8(&wlds[0][c - 2][lane * 8]);
        bf16x8 bz = ld8(&wlds[1][c - 2][lane * 8]);
        bf16x8 bn = ld8(&wlds[2][c - 2][lane * 8]);
        #pragma unroll
        for (int mf = 0; mf < 4; ++mf) {
            bf16x8 a = ld8(Cp + (tA[mf] * 4 + c) * 512 + lane * 8);
            ar[mf]  = mfma16(a, br, ar[mf]);
            az[mf]  = mfma16(a, bz, az[mf]);
            ani[mf] = mfma16(a, bn, ani[mf]);
        }
    }
    for (int c = 0; c < 8; ++c) {        // h part (weight chunks 12..19 -> slots 2..9)
        bf16x8 br = ld8(&wlds[0][2 + c][lane * 8]);
        bf16x8 bz = ld8(&wlds[1][2 + c][lane * 8]);
        bf16x8 bn = ld8(&wlds[2][2 + c][lane * 8]);
        #pragma unroll
        for (int mf = 0; mf < 4; ++mf) {
            bf16x8 a = ld8(hbp + (tA[mf] * 8 + c) * 512 + lane * 8);
            ar[mf]  = mfma16(a, br, ar[mf]);
            az[mf]  = mfma16(a, bz, az[mf]);
            anh[mf] = mfma16(a, bn, anh[mf]);
        }
    }

    const float bir = bih[col] + bhh[col];
    const float biz = bih[256 + col] + bhh[256 + col];
    const float bin = bih[512 + col];
    const float bhn = bhh[512 + col];
    #pragma unroll
    for (int mf = 0; mf < 4; ++mf) if (val[mf])
        #pragma unroll
        for (int r = 0; r < 4; ++r) {
            int row = m64 * 64 + mf * 16 + lq * 4 + r;
            float rg = sigmoidf_(ar[mf][r] + bir);
            float zg = sigmoidf_(az[mf][r] + biz);
            float ng = tanhf_(ani[mf][r] + bin + rg * (anh[mf][r] + bhn));
            float ho = bf2f(hbrow[row * HDIM + col]);
            float hn = (1.0f - zg) * ng + zg * ho;
            out[HN_OFF + row * HDIM + col] = hn;
            Hnp[packIdxEp(tA[mf], lq * 4 + r, t, lr, 8)] = f2bf(hn);
        }
}

// q = h_new @ out_W + out_b. one wave per 16-row tile.
__global__ __launch_bounds__(256) void q_kernel(
    const unsigned short* __restrict__ Hnp, const unsigned short* __restrict__ wop,
    const float* __restrict__ ob, float* __restrict__ out)
{
    int w = blockIdx.x * 4 + (threadIdx.x >> 6);
    if (w >= 1250) w = 1249;
    const int lane = threadIdx.x & 63, lr = lane & 15, lq = lane >> 4;
    f32x4 acc = {0.f, 0.f, 0.f, 0.f};
    for (int c = 0; c < 8; ++c) {
        bf16x8 a = ld8(Hnp + (w * 8 + c) * 512 + lane * 8);
        bf16x8 b = ld8(wop + c * 512 + lane * 8);
        acc = mfma16(a, b, acc);
    }
    float bias = ob[lr];
    #pragma unroll
    for (int r = 0; r < 4; ++r)
        out[Q_OFF + (w * 16 + lq * 4 + r) * ADIM + lr] = acc[r] + bias;
}

extern "C" void kernel_launch(void* const* d_in, const int* in_sizes, int n_in,
                              void* d_out, int out_size, void* d_ws, size_t ws_size,
                              hipStream_t stream) {
    const float* feat = (const float*)d_in[0];
    const float* h    = (const float*)d_in[1];
    const int* src    = (const int*)d_in[2];
    const int* dst    = (const int*)d_in[3];
    const float* w0   = (const float*)d_in[4];
    const float* b0   = (const float*)d_in[5];
    const float* w1   = (const float*)d_in[6];
    const float* b1   = (const float*)d_in[7];
    const float* wm   = (const float*)d_in[8];
    const float* mb   = (const float*)d_in[9];
    const float* wih  = (const float*)d_in[10];
    const float* whh  = (const float*)d_in[11];
    const float* bih  = (const float*)d_in[12];
    const float* bhh  = (const float*)d_in[13];
    const float* wo   = (const float*)d_in[14];
    const float* ob   = (const float*)d_in[15];

    char* ws = (char*)d_ws;
    unsigned short* w0p   = (unsigned short*)(ws + WS_W0P);
    unsigned short* w1p   = (unsigned short*)(ws + WS_W1P);
    unsigned short* wmp   = (unsigned short*)(ws + WS_WMP);
    unsigned short* wgp   = (unsigned short*)(ws + WS_WGP);
    unsigned short* wop   = (unsigned short*)(ws + WS_WOP);
    unsigned short* featp = (unsigned short*)(ws + WS_FEATP);
    unsigned short* hbp   = (unsigned short*)(ws + WS_HBP);
    unsigned short* X0p   = (unsigned short*)(ws + WS_X0P);
    unsigned short* Xp    = (unsigned short*)(ws + WS_XP);
    unsigned short* Mn    = (unsigned short*)(ws + WS_MN);
    unsigned short* Cp    = (unsigned short*)(ws + WS_CP);
    unsigned short* Hnp   = (unsigned short*)(ws + WS_HNP);
    unsigned short* hbrow = (unsigned short*)(ws + WS_HBROW);
    int* deg              = (int*)(ws + WS_DEG);
    int* off              = (int*)(ws + WS_OFF);
    int* cur              = (int*)(ws + WS_CUR);
    int* bucket           = (int*)(ws + WS_BUCKET);
    float* out            = (float*)d_out;

    hipMemsetAsync(deg, 0, N_NODES * sizeof(int), stream);
    hipLaunchKernelGGL(setup_kernel, dim3(1280), dim3(256), 0, stream,
                       feat, h, w0, w1, wm, wih, whh, wo, dst,
                       featp, hbp, hbrow, w0p, w1p, wmp, wgp, wop, deg);
    hipLaunchKernelGGL(scan_kernel, dim3(1), dim3(1024), 0, stream, deg, off, cur);
    hipLaunchKernelGGL(scatter_idx, dim3((N_EDGES + 255) / 256), dim3(256), 0, stream, src, dst, cur, bucket);
    hipLaunchKernelGGL(enc0_kernel, dim3(1252), dim3(256), 0, stream, featp, w0p, b0, X0p);
    hipLaunchKernelGGL(enc1_kernel, dim3(79 * 16), dim3(256), 0, stream, X0p, w1p, b1, Xp);
    hipLaunchKernelGGL(msg_kernel, dim3(79 * 8), dim3(256), 0, stream, Xp, hbp, wmp, mb, Mn);
    hipLaunchKernelGGL(aggregate_kernel, dim3((N_NODES + 3) / 4), dim3(256), 0, stream,
                       off, deg, bucket, Mn, Cp);
    hipLaunchKernelGGL(gru_kernel, dim3(79 * 16), dim3(256), 0, stream,
                       Xp, Cp, hbp, hbrow, wgp, bih, bhh, Hnp, out);
    hipLaunchKernelGGL(q_kernel, dim3(313), dim3(256), 0, stream, Hnp, wop, ob, out);
}

// Round 10
// 318.661 us; speedup vs baseline: 1.0955x; 1.0955x over previous
//
#include <hip/hip_runtime.h>

#define N_NODES 20000
#define N_EDGES 640000
#define OBS 64
#define HDIM 256
#define MSGD 128
#define ADIM 16
#define Q_OFF 0
#define HN_OFF (N_NODES * ADIM)   // 320000

typedef __bf16 bf16x8 __attribute__((ext_vector_type(8)));
typedef float  f32x4  __attribute__((ext_vector_type(4)));

__device__ __forceinline__ unsigned short f2bf(float f) {
    union { float f; unsigned int i; } v; v.f = f;
    unsigned int i = v.i;
    return (unsigned short)((i + 0x7fffu + ((i >> 16) & 1u)) >> 16);
}
__device__ __forceinline__ float bf2f(unsigned short u) {
    union { unsigned int i; float f; } v; v.i = ((unsigned int)u) << 16; return v.f;
}
__device__ __forceinline__ bf16x8 ld8(const unsigned short* p) {
    bf16x8 r;
    __builtin_memcpy(&r, __builtin_assume_aligned(p, 16), 16);
    return r;
}
__device__ __forceinline__ f32x4 mfma16(bf16x8 a, bf16x8 b, f32x4 c) {
    return __builtin_amdgcn_mfma_f32_16x16x32_bf16(a, b, c, 0, 0, 0);
}
__device__ __forceinline__ float sigmoidf_(float x) { return 1.0f / (1.0f + __expf(-x)); }
__device__ __forceinline__ float tanhf_(float x) { return 2.0f / (1.0f + __expf(-2.0f * x)) - 1.0f; }

// fragment-packed layout: element (row,k) of a K-major matrix, Kc=K/32:
__device__ __forceinline__ int packIdx(int row, int k, int Kc) {
    return ((row >> 4) * Kc + (k >> 5)) * 512 + (((k >> 3) & 3) * 16 + (row & 15)) * 8 + (k & 7);
}
__device__ __forceinline__ int packIdxEp(int tile, int rlow, int t, int lr, int Kc) {
    return (tile * Kc + (t >> 1)) * 512 + (((t & 1) * 2 + (lr >> 3)) * 16 + rlow) * 8 + (lr & 7);
}

// ---------------- ws layout (bytes) ----------------
#define WS_W0P    0u
#define WS_W1P    32768u
#define WS_WMP    163840u
#define WS_WGP    294912u
#define WS_WOP    1277952u
#define WS_FEATP  1286144u
#define WS_HBP    3846144u
#define WS_X0P    14086144u
#define WS_XP     24326144u
#define WS_MN     34566144u
#define WS_CP     39686144u
#define WS_HNP    44806144u
#define WS_DEG    55046144u
#define WS_OFF    55126144u
#define WS_CUR    55206144u
#define WS_BUCKET 55286144u
#define WS_HBROW  57846144u   // row-major 20000 x 256 bf16 (end 68086144)

#define GATE_STRIDE 163840

// fused setup: feat/h -> bf16 (packed + row-major h), weight packing, dst histogram.
__global__ __launch_bounds__(256) void setup_kernel(
    const float* __restrict__ feat, const float* __restrict__ h,
    const float* __restrict__ w0, const float* __restrict__ w1, const float* __restrict__ wm,
    const float* __restrict__ wih, const float* __restrict__ whh, const float* __restrict__ wo,
    const int* __restrict__ dst,
    unsigned short* __restrict__ featp, unsigned short* __restrict__ hbp,
    unsigned short* __restrict__ hbrow,
    unsigned short* __restrict__ w0p, unsigned short* __restrict__ w1p,
    unsigned short* __restrict__ wmp, unsigned short* __restrict__ wgp,
    unsigned short* __restrict__ wop, int* __restrict__ deg)
{
    int tid = blockIdx.x * 256 + threadIdx.x;
    int np = gridDim.x * 256;
    for (int ch = tid; ch < N_NODES * OBS / 8; ch += np) {
        int row = ch >> 3, k = (ch & 7) * 8;
        const float4* p = (const float4*)(feat + row * OBS + k);
        float4 a = p[0], b = p[1];
        union { unsigned short u[8]; uint4 v; } r;
        r.u[0]=f2bf(a.x); r.u[1]=f2bf(a.y); r.u[2]=f2bf(a.z); r.u[3]=f2bf(a.w);
        r.u[4]=f2bf(b.x); r.u[5]=f2bf(b.y); r.u[6]=f2bf(b.z); r.u[7]=f2bf(b.w);
        *(uint4*)(featp + packIdx(row, k, 2)) = r.v;
    }
    for (int ch = tid; ch < N_NODES * HDIM / 8; ch += np) {
        int row = ch >> 5, k = (ch & 31) * 8;
        const float4* p = (const float4*)(h + row * HDIM + k);
        float4 a = p[0], b = p[1];
        union { unsigned short u[8]; uint4 v; } r;
        r.u[0]=f2bf(a.x); r.u[1]=f2bf(a.y); r.u[2]=f2bf(a.z); r.u[3]=f2bf(a.w);
        r.u[4]=f2bf(b.x); r.u[5]=f2bf(b.y); r.u[6]=f2bf(b.z); r.u[7]=f2bf(b.w);
        *(uint4*)(hbp + packIdx(row, k, 8)) = r.v;
        *(uint4*)(hbrow + row * HDIM + k) = r.v;
    }
    for (int i = tid; i < 64 * 256; i += np)  { int k = i >> 8, n = i & 255; w0p[packIdx(n, k, 2)]  = f2bf(w0[i]); }
    for (int i = tid; i < 256 * 256; i += np) { int k = i >> 8, n = i & 255; w1p[packIdx(n, k, 8)]  = f2bf(w1[i]); }
    for (int i = tid; i < 512 * 128; i += np) { int k = i >> 7, n = i & 127; wmp[packIdx(n, k, 16)] = f2bf(wm[i]); }
    for (int i = tid; i < 384 * 768; i += np) {
        int k = i / 768, c3 = i % 768;
        wgp[(c3 >> 8) * GATE_STRIDE + packIdx(c3 & 255, k, 20)] = f2bf(wih[i]);
    }
    for (int i = tid; i < 256 * 768; i += np) {
        int k = i / 768, c3 = i % 768;
        wgp[(c3 >> 8) * GATE_STRIDE + packIdx(c3 & 255, 384 + k, 20)] = f2bf(whh[i]);
    }
    for (int i = tid; i < 256 * 16; i += np)  { int k = i >> 4, n = i & 15; wop[packIdx(n, k, 8)] = f2bf(wo[i]); }
    for (int i = tid; i < N_EDGES; i += np) atomicAdd(&deg[dst[i]], 1);
}

__global__ __launch_bounds__(1024) void scan_kernel(const int* __restrict__ deg,
                                                    int* __restrict__ off, int* __restrict__ cur) {
    __shared__ int part[1024];
    const int t = threadIdx.x;
    const int base = t * 20;
    int s = 0;
    #pragma unroll
    for (int i = 0; i < 20; ++i) { int idx = base + i; if (idx < N_NODES) s += deg[idx]; }
    part[t] = s;
    __syncthreads();
    int acc = s;
    for (int d = 1; d < 1024; d <<= 1) {
        int v = (t >= d) ? part[t - d] : 0;
        __syncthreads();
        acc += v; part[t] = acc;
        __syncthreads();
    }
    int run = acc - s;
    for (int i = 0; i < 20; ++i) {
        int idx = base + i;
        if (idx < N_NODES) { off[idx] = run; cur[idx] = run; run += deg[idx]; }
    }
}

__global__ __launch_bounds__(256) void scatter_idx(const int* __restrict__ src, const int* __restrict__ dst,
                                                   int* __restrict__ cur, int* __restrict__ bucket) {
    int i = blockIdx.x * 256 + threadIdx.x;
    if (i < N_EDGES) {
        int d = dst[i];
        int pos = atomicAdd(&cur[d], 1);
        bucket[pos] = src[i];
    }
}

// enc0: X0 = relu(feat @ W0 + b0). flat m64-major waves. 1252 blocks.
__global__ __launch_bounds__(256) void enc0_kernel(
    const unsigned short* __restrict__ featp, const unsigned short* __restrict__ w0p,
    const float* __restrict__ b0, unsigned short* __restrict__ X0p)
{
    const int w = blockIdx.x * 4 + (threadIdx.x >> 6);
    const int lane = threadIdx.x & 63, lr = lane & 15, lq = lane >> 4;
    const int m64 = w >> 4, t = w & 15;
    int tA[4]; bool val[4];
    #pragma unroll
    for (int mf = 0; mf < 4; ++mf) { int tl = m64 * 4 + mf; val[mf] = tl < 1250; tA[mf] = val[mf] ? tl : 1249; }
    f32x4 acc[4] = {{0,0,0,0},{0,0,0,0},{0,0,0,0},{0,0,0,0}};
    for (int c = 0; c < 2; ++c) {
        bf16x8 b = ld8(w0p + (t * 2 + c) * 512 + lane * 8);
        #pragma unroll
        for (int mf = 0; mf < 4; ++mf) {
            bf16x8 a = ld8(featp + (tA[mf] * 2 + c) * 512 + lane * 8);
            acc[mf] = mfma16(a, b, acc[mf]);
        }
    }
    float bias = b0[t * 16 + lr];
    #pragma unroll
    for (int mf = 0; mf < 4; ++mf) if (val[mf])
        #pragma unroll
        for (int r = 0; r < 4; ++r)
            X0p[packIdxEp(tA[mf], lq * 4 + r, t, lr, 8)] = f2bf(fmaxf(acc[mf][r] + bias, 0.f));
}

// enc1: X = relu(X0 @ W1 + b1). flat m64-major waves. 1252 blocks.
__global__ __launch_bounds__(256) void enc1_kernel(
    const unsigned short* __restrict__ X0p, const unsigned short* __restrict__ w1p,
    const float* __restrict__ b1, unsigned short* __restrict__ Xp)
{
    const int w = blockIdx.x * 4 + (threadIdx.x >> 6);
    const int lane = threadIdx.x & 63, lr = lane & 15, lq = lane >> 4;
    const int m64 = w >> 4, t = w & 15;
    int tA[4]; bool val[4];
    #pragma unroll
    for (int mf = 0; mf < 4; ++mf) { int tl = m64 * 4 + mf; val[mf] = tl < 1250; tA[mf] = val[mf] ? tl : 1249; }
    f32x4 acc[4] = {{0,0,0,0},{0,0,0,0},{0,0,0,0},{0,0,0,0}};
    for (int c = 0; c < 8; ++c) {
        bf16x8 b = ld8(w1p + (t * 8 + c) * 512 + lane * 8);
        #pragma unroll
        for (int mf = 0; mf < 4; ++mf) {
            bf16x8 a = ld8(X0p + (tA[mf] * 8 + c) * 512 + lane * 8);
            acc[mf] = mfma16(a, b, acc[mf]);
        }
    }
    float bias = b1[t * 16 + lr];
    #pragma unroll
    for (int mf = 0; mf < 4; ++mf) if (val[mf])
        #pragma unroll
        for (int r = 0; r < 4; ++r)
            Xp[packIdxEp(tA[mf], lq * 4 + r, t, lr, 8)] = f2bf(fmaxf(acc[mf][r] + bias, 0.f));
}

// msg: Mnode = X @ Wx + h @ Wh + mb -> row-major. flat m64-major waves. 626 blocks.
__global__ __launch_bounds__(256) void msg_kernel(
    const unsigned short* __restrict__ Xp, const unsigned short* __restrict__ hbp,
    const unsigned short* __restrict__ wmp, const float* __restrict__ mb,
    unsigned short* __restrict__ Mn)
{
    const int w = blockIdx.x * 4 + (threadIdx.x >> 6);
    const int lane = threadIdx.x & 63, lr = lane & 15, lq = lane >> 4;
    const int m64 = w >> 3, t = w & 7;
    const int col = t * 16 + lr;
    int tA[4]; bool val[4];
    #pragma unroll
    for (int mf = 0; mf < 4; ++mf) { int tl = m64 * 4 + mf; val[mf] = tl < 1250; tA[mf] = val[mf] ? tl : 1249; }
    f32x4 acc[4] = {{0,0,0,0},{0,0,0,0},{0,0,0,0},{0,0,0,0}};
    for (int c = 0; c < 8; ++c) {            // X part (k 0..255)
        bf16x8 b = ld8(wmp + (t * 16 + c) * 512 + lane * 8);
        #pragma unroll
        for (int mf = 0; mf < 4; ++mf) {
            bf16x8 a = ld8(Xp + (tA[mf] * 8 + c) * 512 + lane * 8);
            acc[mf] = mfma16(a, b, acc[mf]);
        }
    }
    for (int c = 0; c < 8; ++c) {            // h part (k 256..511)
        bf16x8 b = ld8(wmp + (t * 16 + 8 + c) * 512 + lane * 8);
        #pragma unroll
        for (int mf = 0; mf < 4; ++mf) {
            bf16x8 a = ld8(hbp + (tA[mf] * 8 + c) * 512 + lane * 8);
            acc[mf] = mfma16(a, b, acc[mf]);
        }
    }
    float bias = mb[col];
    #pragma unroll
    for (int mf = 0; mf < 4; ++mf) if (val[mf])
        #pragma unroll
        for (int r = 0; r < 4; ++r) {
            int row = m64 * 64 + mf * 16 + lq * 4 + r;
            Mn[row * MSGD + col] = f2bf(acc[mf][r] + bias);
        }
}

// one wave per node: gather Mn rows, mean, write packed C row. 8-deep MLP unroll.
__global__ __launch_bounds__(256) void aggregate_kernel(
    const int* __restrict__ off, const int* __restrict__ deg,
    const int* __restrict__ bucket, const unsigned short* __restrict__ Mn,
    unsigned short* __restrict__ Cp)
{
    const int wave = threadIdx.x >> 6;
    const int lane = threadIdx.x & 63;
    const int node = blockIdx.x * 4 + wave;
    if (node >= N_NODES) return;
    const int o = off[node], dg = deg[node];
    float s0 = 0.f, s1 = 0.f;
    const unsigned int* mn = (const unsigned int*)Mn;
    int j = 0;
    for (; j + 8 <= dg; j += 8) {
        int ix[8];
        #pragma unroll
        for (int u = 0; u < 8; ++u) ix[u] = bucket[o + j + u];
        unsigned int pk[8];
        #pragma unroll
        for (int u = 0; u < 8; ++u) pk[u] = mn[ix[u] * 64 + lane];
        #pragma unroll
        for (int u = 0; u < 8; ++u) {
            s0 += bf2f((unsigned short)(pk[u] & 0xffffu));
            s1 += bf2f((unsigned short)(pk[u] >> 16));
        }
    }
    for (; j < dg; ++j) {
        int sidx = bucket[o + j];
        unsigned int pk = mn[sidx * 64 + lane];
        s0 += bf2f((unsigned short)(pk & 0xffffu));
        s1 += bf2f((unsigned short)(pk >> 16));
    }
    float invc = 1.0f / fmaxf((float)dg, 1.0f);
    unsigned int outpk = ((unsigned int)f2bf(s1 * invc) << 16) | (unsigned int)f2bf(s0 * invc);
    *(unsigned int*)(Cp + packIdx(node, 2 * lane, 4)) = outpk;
}

// GRU gates + h_new. flat m64-major waves, direct global B loads (R6 form). 1252 blocks.
__global__ __launch_bounds__(256) void gru_kernel(
    const unsigned short* __restrict__ Xp, const unsigned short* __restrict__ Cp,
    const unsigned short* __restrict__ hbp, const unsigned short* __restrict__ hbrow,
    const unsigned short* __restrict__ wgp,
    const float* __restrict__ bih, const float* __restrict__ bhh,
    unsigned short* __restrict__ Hnp, float* __restrict__ out)
{
    const int w = blockIdx.x * 4 + (threadIdx.x >> 6);
    const int lane = threadIdx.x & 63, lr = lane & 15, lq = lane >> 4;
    const int m64 = w >> 4, t = w & 15;
    const int col = t * 16 + lr;
    int tA[4]; bool val[4];
    #pragma unroll
    for (int mf = 0; mf < 4; ++mf) { int tl = m64 * 4 + mf; val[mf] = tl < 1250; tA[mf] = val[mf] ? tl : 1249; }

    f32x4 ar[4]  = {{0,0,0,0},{0,0,0,0},{0,0,0,0},{0,0,0,0}};
    f32x4 az[4]  = {{0,0,0,0},{0,0,0,0},{0,0,0,0},{0,0,0,0}};
    f32x4 ani[4] = {{0,0,0,0},{0,0,0,0},{0,0,0,0},{0,0,0,0}};
    f32x4 anh[4] = {{0,0,0,0},{0,0,0,0},{0,0,0,0},{0,0,0,0}};

    const unsigned short* wr = wgp + 0 * GATE_STRIDE + t * 20 * 512 + lane * 8;
    const unsigned short* wz = wgp + 1 * GATE_STRIDE + t * 20 * 512 + lane * 8;
    const unsigned short* wn = wgp + 2 * GATE_STRIDE + t * 20 * 512 + lane * 8;

    for (int c = 0; c < 8; ++c) {        // X part
        bf16x8 br = ld8(wr + c * 512);
        bf16x8 bz = ld8(wz + c * 512);
        bf16x8 bn = ld8(wn + c * 512);
        #pragma unroll
        for (int mf = 0; mf < 4; ++mf) {
            bf16x8 a = ld8(Xp + (tA[mf] * 8 + c) * 512 + lane * 8);
            ar[mf]  = mfma16(a, br, ar[mf]);
            az[mf]  = mfma16(a, bz, az[mf]);
            ani[mf] = mfma16(a, bn, ani[mf]);
        }
    }
    for (int c = 0; c < 4; ++c) {        // C part
        bf16x8 br = ld8(wr + (8 + c) * 512);
        bf16x8 bz = ld8(wz + (8 + c) * 512);
        bf16x8 bn = ld8(wn + (8 + c) * 512);
        #pragma unroll
        for (int mf = 0; mf < 4; ++mf) {
            bf16x8 a = ld8(Cp + (tA[mf] * 4 + c) * 512 + lane * 8);
            ar[mf]  = mfma16(a, br, ar[mf]);
            az[mf]  = mfma16(a, bz, az[mf]);
            ani[mf] = mfma16(a, bn, ani[mf]);
        }
    }
    for (int c = 0; c < 8; ++c) {        // h part; n-gate separate accumulator
        bf16x8 br = ld8(wr + (12 + c) * 512);
        bf16x8 bz = ld8(wz + (12 + c) * 512);
        bf16x8 bn = ld8(wn + (12 + c) * 512);
        #pragma unroll
        for (int mf = 0; mf < 4; ++mf) {
            bf16x8 a = ld8(hbp + (tA[mf] * 8 + c) * 512 + lane * 8);
            ar[mf]  = mfma16(a, br, ar[mf]);
            az[mf]  = mfma16(a, bz, az[mf]);
            anh[mf] = mfma16(a, bn, anh[mf]);
        }
    }

    const float bir = bih[col] + bhh[col];
    const float biz = bih[256 + col] + bhh[256 + col];
    const float bin = bih[512 + col];
    const float bhn = bhh[512 + col];
    #pragma unroll
    for (int mf = 0; mf < 4; ++mf) if (val[mf])
        #pragma unroll
        for (int r = 0; r < 4; ++r) {
            int row = m64 * 64 + mf * 16 + lq * 4 + r;
            float rg = sigmoidf_(ar[mf][r] + bir);
            float zg = sigmoidf_(az[mf][r] + biz);
            float ng = tanhf_(ani[mf][r] + bin + rg * (anh[mf][r] + bhn));
            float ho = bf2f(hbrow[row * HDIM + col]);
            float hn = (1.0f - zg) * ng + zg * ho;
            out[HN_OFF + row * HDIM + col] = hn;
            Hnp[packIdxEp(tA[mf], lq * 4 + r, t, lr, 8)] = f2bf(hn);
        }
}

// q = h_new @ out_W + out_b. one wave per 16-row tile.
__global__ __launch_bounds__(256) void q_kernel(
    const unsigned short* __restrict__ Hnp, const unsigned short* __restrict__ wop,
    const float* __restrict__ ob, float* __restrict__ out)
{
    int w = blockIdx.x * 4 + (threadIdx.x >> 6);
    if (w >= 1250) w = 1249;
    const int lane = threadIdx.x & 63, lr = lane & 15, lq = lane >> 4;
    f32x4 acc = {0.f, 0.f, 0.f, 0.f};
    for (int c = 0; c < 8; ++c) {
        bf16x8 a = ld8(Hnp + (w * 8 + c) * 512 + lane * 8);
        bf16x8 b = ld8(wop + c * 512 + lane * 8);
        acc = mfma16(a, b, acc);
    }
    float bias = ob[lr];
    #pragma unroll
    for (int r = 0; r < 4; ++r)
        out[Q_OFF + (w * 16 + lq * 4 + r) * ADIM + lr] = acc[r] + bias;
}

extern "C" void kernel_launch(void* const* d_in, const int* in_sizes, int n_in,
                              void* d_out, int out_size, void* d_ws, size_t ws_size,
                              hipStream_t stream) {
    const float* feat = (const float*)d_in[0];
    const float* h    = (const float*)d_in[1];
    const int* src    = (const int*)d_in[2];
    const int* dst    = (const int*)d_in[3];
    const float* w0   = (const float*)d_in[4];
    const float* b0   = (const float*)d_in[5];
    const float* w1   = (const float*)d_in[6];
    const float* b1   = (const float*)d_in[7];
    const float* wm   = (const float*)d_in[8];
    const float* mb   = (const float*)d_in[9];
    const float* wih  = (const float*)d_in[10];
    const float* whh  = (const float*)d_in[11];
    const float* bih  = (const float*)d_in[12];
    const float* bhh  = (const float*)d_in[13];
    const float* wo   = (const float*)d_in[14];
    const float* ob   = (const float*)d_in[15];

    char* ws = (char*)d_ws;
    unsigned short* w0p   = (unsigned short*)(ws + WS_W0P);
    unsigned short* w1p   = (unsigned short*)(ws + WS_W1P);
    unsigned short* wmp   = (unsigned short*)(ws + WS_WMP);
    unsigned short* wgp   = (unsigned short*)(ws + WS_WGP);
    unsigned short* wop   = (unsigned short*)(ws + WS_WOP);
    unsigned short* featp = (unsigned short*)(ws + WS_FEATP);
    unsigned short* hbp   = (unsigned short*)(ws + WS_HBP);
    unsigned short* X0p   = (unsigned short*)(ws + WS_X0P);
    unsigned short* Xp    = (unsigned short*)(ws + WS_XP);
    unsigned short* Mn    = (unsigned short*)(ws + WS_MN);
    unsigned short* Cp    = (unsigned short*)(ws + WS_CP);
    unsigned short* Hnp   = (unsigned short*)(ws + WS_HNP);
    unsigned short* hbrow = (unsigned short*)(ws + WS_HBROW);
    int* deg              = (int*)(ws + WS_DEG);
    int* off              = (int*)(ws + WS_OFF);
    int* cur              = (int*)(ws + WS_CUR);
    int* bucket           = (int*)(ws + WS_BUCKET);
    float* out            = (float*)d_out;

    hipMemsetAsync(deg, 0, N_NODES * sizeof(int), stream);
    hipLaunchKernelGGL(setup_kernel, dim3(1280), dim3(256), 0, stream,
                       feat, h, w0, w1, wm, wih, whh, wo, dst,
                       featp, hbp, hbrow, w0p, w1p, wmp, wgp, wop, deg);
    hipLaunchKernelGGL(scan_kernel, dim3(1), dim3(1024), 0, stream, deg, off, cur);
    hipLaunchKernelGGL(scatter_idx, dim3((N_EDGES + 255) / 256), dim3(256), 0, stream, src, dst, cur, bucket);
    hipLaunchKernelGGL(enc0_kernel, dim3(1252), dim3(256), 0, stream, featp, w0p, b0, X0p);
    hipLaunchKernelGGL(enc1_kernel, dim3(1252), dim3(256), 0, stream, X0p, w1p, b1, Xp);
    hipLaunchKernelGGL(msg_kernel, dim3(626), dim3(256), 0, stream, Xp, hbp, wmp, mb, Mn);
    hipLaunchKernelGGL(aggregate_kernel, dim3((N_NODES + 3) / 4), dim3(256), 0, stream,
                       off, deg, bucket, Mn, Cp);
    hipLaunchKernelGGL(gru_kernel, dim3(1252), dim3(256), 0, stream,
                       Xp, Cp, hbp, hbrow, wgp, bih, bhh, Hnp, out);
    hipLaunchKernelGGL(q_kernel, dim3(313), dim3(256), 0, stream, Hnp, wop, ob, out);
}

// Round 11
// 303.947 us; speedup vs baseline: 1.1486x; 1.0484x over previous
//
#include <hip/hip_runtime.h>

#define N_NODES 20000
#define N_EDGES 640000
#define OBS 64
#define HDIM 256
#define MSGD 128
#define ADIM 16
#define Q_OFF 0
#define HN_OFF (N_NODES * ADIM)   // 320000

typedef __bf16 bf16x8 __attribute__((ext_vector_type(8)));
typedef float  f32x4  __attribute__((ext_vector_type(4)));

__device__ __forceinline__ unsigned short f2bf(float f) {
    union { float f; unsigned int i; } v; v.f = f;
    unsigned int i = v.i;
    return (unsigned short)((i + 0x7fffu + ((i >> 16) & 1u)) >> 16);
}
__device__ __forceinline__ float bf2f(unsigned short u) {
    union { unsigned int i; float f; } v; v.i = ((unsigned int)u) << 16; return v.f;
}
__device__ __forceinline__ bf16x8 ld8(const unsigned short* p) {
    bf16x8 r;
    __builtin_memcpy(&r, __builtin_assume_aligned(p, 16), 16);
    return r;
}
__device__ __forceinline__ f32x4 mfma16(bf16x8 a, bf16x8 b, f32x4 c) {
    return __builtin_amdgcn_mfma_f32_16x16x32_bf16(a, b, c, 0, 0, 0);
}
__device__ __forceinline__ float sigmoidf_(float x) { return 1.0f / (1.0f + __expf(-x)); }
__device__ __forceinline__ float tanhf_(float x) { return 2.0f / (1.0f + __expf(-2.0f * x)) - 1.0f; }

// fragment-packed layout: element (row,k) of a K-major matrix, Kc=K/32:
__device__ __forceinline__ int packIdx(int row, int k, int Kc) {
    return ((row >> 4) * Kc + (k >> 5)) * 512 + (((k >> 3) & 3) * 16 + (row & 15)) * 8 + (k & 7);
}
__device__ __forceinline__ int packIdxEp(int tile, int rlow, int t, int lr, int Kc) {
    return (tile * Kc + (t >> 1)) * 512 + (((t & 1) * 2 + (lr >> 3)) * 16 + rlow) * 8 + (lr & 7);
}
// block-local LDS variant (tile folded out): chunk = t>>1
__device__ __forceinline__ int packIdxLoc(int rlow, int t, int lr) {
    return (t >> 1) * 512 + (((t & 1) * 2 + (lr >> 3)) * 16 + rlow) * 8 + (lr & 7);
}

// ---------------- ws layout (bytes) ----------------
#define WS_W0P    0u
#define WS_W1P    32768u
#define WS_WMP    163840u
#define WS_WGP    294912u
#define WS_WOP    1277952u
#define WS_FEATP  1286144u
#define WS_HBP    3846144u
#define WS_XP     24326144u
#define WS_MN     34566144u
#define WS_CP     39686144u
#define WS_HNP    44806144u
#define WS_DEG    55046144u
#define WS_OFF    55126144u
#define WS_CUR    55206144u
#define WS_BUCKET 55286144u   // 640000 int (end 57846144)

#define GATE_STRIDE 163840

// fused setup: feat/h -> packed bf16, weight packing, dst histogram.
__global__ __launch_bounds__(256) void setup_kernel(
    const float* __restrict__ feat, const float* __restrict__ h,
    const float* __restrict__ w0, const float* __restrict__ w1, const float* __restrict__ wm,
    const float* __restrict__ wih, const float* __restrict__ whh, const float* __restrict__ wo,
    const int* __restrict__ dst,
    unsigned short* __restrict__ featp, unsigned short* __restrict__ hbp,
    unsigned short* __restrict__ w0p, unsigned short* __restrict__ w1p,
    unsigned short* __restrict__ wmp, unsigned short* __restrict__ wgp,
    unsigned short* __restrict__ wop, int* __restrict__ deg)
{
    int tid = blockIdx.x * 256 + threadIdx.x;
    int np = gridDim.x * 256;
    for (int ch = tid; ch < N_NODES * OBS / 8; ch += np) {
        int row = ch >> 3, k = (ch & 7) * 8;
        const float4* p = (const float4*)(feat + row * OBS + k);
        float4 a = p[0], b = p[1];
        union { unsigned short u[8]; uint4 v; } r;
        r.u[0]=f2bf(a.x); r.u[1]=f2bf(a.y); r.u[2]=f2bf(a.z); r.u[3]=f2bf(a.w);
        r.u[4]=f2bf(b.x); r.u[5]=f2bf(b.y); r.u[6]=f2bf(b.z); r.u[7]=f2bf(b.w);
        *(uint4*)(featp + packIdx(row, k, 2)) = r.v;
    }
    for (int ch = tid; ch < N_NODES * HDIM / 8; ch += np) {
        int row = ch >> 5, k = (ch & 31) * 8;
        const float4* p = (const float4*)(h + row * HDIM + k);
        float4 a = p[0], b = p[1];
        union { unsigned short u[8]; uint4 v; } r;
        r.u[0]=f2bf(a.x); r.u[1]=f2bf(a.y); r.u[2]=f2bf(a.z); r.u[3]=f2bf(a.w);
        r.u[4]=f2bf(b.x); r.u[5]=f2bf(b.y); r.u[6]=f2bf(b.z); r.u[7]=f2bf(b.w);
        *(uint4*)(hbp + packIdx(row, k, 8)) = r.v;
    }
    for (int i = tid; i < 64 * 256; i += np)  { int k = i >> 8, n = i & 255; w0p[packIdx(n, k, 2)]  = f2bf(w0[i]); }
    for (int i = tid; i < 256 * 256; i += np) { int k = i >> 8, n = i & 255; w1p[packIdx(n, k, 8)]  = f2bf(w1[i]); }
    for (int i = tid; i < 512 * 128; i += np) { int k = i >> 7, n = i & 127; wmp[packIdx(n, k, 16)] = f2bf(wm[i]); }
    for (int i = tid; i < 384 * 768; i += np) {
        int k = i / 768, c3 = i % 768;
        wgp[(c3 >> 8) * GATE_STRIDE + packIdx(c3 & 255, k, 20)] = f2bf(wih[i]);
    }
    for (int i = tid; i < 256 * 768; i += np) {
        int k = i / 768, c3 = i % 768;
        wgp[(c3 >> 8) * GATE_STRIDE + packIdx(c3 & 255, 384 + k, 20)] = f2bf(whh[i]);
    }
    for (int i = tid; i < 256 * 16; i += np)  { int k = i >> 4, n = i & 15; wop[packIdx(n, k, 8)] = f2bf(wo[i]); }
    for (int i = tid; i < N_EDGES; i += np) atomicAdd(&deg[dst[i]], 1);
}

__global__ __launch_bounds__(1024) void scan_kernel(const int* __restrict__ deg,
                                                    int* __restrict__ off, int* __restrict__ cur) {
    __shared__ int part[1024];
    const int t = threadIdx.x;
    const int base = t * 20;
    int s = 0;
    #pragma unroll
    for (int i = 0; i < 20; ++i) { int idx = base + i; if (idx < N_NODES) s += deg[idx]; }
    part[t] = s;
    __syncthreads();
    int acc = s;
    for (int d = 1; d < 1024; d <<= 1) {
        int v = (t >= d) ? part[t - d] : 0;
        __syncthreads();
        acc += v; part[t] = acc;
        __syncthreads();
    }
    int run = acc - s;
    for (int i = 0; i < 20; ++i) {
        int idx = base + i;
        if (idx < N_NODES) { off[idx] = run; cur[idx] = run; run += deg[idx]; }
    }
}

__global__ __launch_bounds__(256) void scatter_idx(const int* __restrict__ src, const int* __restrict__ dst,
                                                   int* __restrict__ cur, int* __restrict__ bucket) {
    int i = blockIdx.x * 256 + threadIdx.x;
    if (i < N_EDGES) {
        int d = dst[i];
        int pos = atomicAdd(&cur[d], 1);
        bucket[pos] = src[i];
    }
}

// fused encoder: enc0 -> enc1 -> msg. One block = 32-row slab (2 tiles);
// X0 and X live in LDS (16 KB each); X also written packed to global for gru.
// grid 626 blocks x 4 waves.
__global__ __launch_bounds__(256) void enc_fused_kernel(
    const unsigned short* __restrict__ featp, const unsigned short* __restrict__ hbp,
    const unsigned short* __restrict__ w0p, const float* __restrict__ b0,
    const unsigned short* __restrict__ w1p, const float* __restrict__ b1,
    const unsigned short* __restrict__ wmp, const float* __restrict__ mb,
    unsigned short* __restrict__ Xp, unsigned short* __restrict__ Mn)
{
    const int wave = threadIdx.x >> 6;
    const int lane = threadIdx.x & 63, lr = lane & 15, lq = lane >> 4;
    const int m32 = blockIdx.x;          // 0..625
    int tG[2]; bool val[2];
    #pragma unroll
    for (int mf = 0; mf < 2; ++mf) { int tl = m32 * 2 + mf; val[mf] = tl < 1250; tG[mf] = val[mf] ? tl : 1249; }

    __shared__ __align__(16) unsigned short x0l[2][8][512];  // 16 KB
    __shared__ __align__(16) unsigned short x1l[2][8][512];  // 16 KB

    // ---- Stage A: X0 = relu(feat @ W0 + b0) -> LDS ----
    for (int i = 0; i < 4; ++i) {
        const int t = wave * 4 + i;
        f32x4 acc[2] = {{0,0,0,0},{0,0,0,0}};
        for (int c = 0; c < 2; ++c) {
            bf16x8 b = ld8(w0p + (t * 2 + c) * 512 + lane * 8);
            #pragma unroll
            for (int mf = 0; mf < 2; ++mf) {
                bf16x8 a = ld8(featp + (tG[mf] * 2 + c) * 512 + lane * 8);
                acc[mf] = mfma16(a, b, acc[mf]);
            }
        }
        float bias = b0[t * 16 + lr];
        #pragma unroll
        for (int mf = 0; mf < 2; ++mf)
            #pragma unroll
            for (int r = 0; r < 4; ++r)
                (&x0l[mf][0][0])[packIdxLoc(lq * 4 + r, t, lr)] = f2bf(fmaxf(acc[mf][r] + bias, 0.f));
    }
    __syncthreads();
    // ---- Stage B: X = relu(X0 @ W1 + b1) -> LDS + packed global ----
    for (int i = 0; i < 4; ++i) {
        const int t = wave * 4 + i;
        f32x4 acc[2] = {{0,0,0,0},{0,0,0,0}};
        for (int c = 0; c < 8; ++c) {
            bf16x8 b = ld8(w1p + (t * 8 + c) * 512 + lane * 8);
            #pragma unroll
            for (int mf = 0; mf < 2; ++mf) {
                bf16x8 a = ld8(&x0l[mf][c][lane * 8]);
                acc[mf] = mfma16(a, b, acc[mf]);
            }
        }
        float bias = b1[t * 16 + lr];
        #pragma unroll
        for (int mf = 0; mf < 2; ++mf)
            #pragma unroll
            for (int r = 0; r < 4; ++r) {
                unsigned short xb = f2bf(fmaxf(acc[mf][r] + bias, 0.f));
                (&x1l[mf][0][0])[packIdxLoc(lq * 4 + r, t, lr)] = xb;
                if (val[mf]) Xp[packIdxEp(tG[mf], lq * 4 + r, t, lr, 8)] = xb;
            }
    }
    __syncthreads();
    // ---- Stage C: Mnode = X @ Wx + h @ Wh + mb -> row-major global ----
    for (int i = 0; i < 2; ++i) {
        const int t = wave * 2 + i;          // 0..7
        const int col = t * 16 + lr;
        f32x4 acc[2] = {{0,0,0,0},{0,0,0,0}};
        for (int c = 0; c < 8; ++c) {        // X part (k 0..255), A from LDS
            bf16x8 b = ld8(wmp + (t * 16 + c) * 512 + lane * 8);
            #pragma unroll
            for (int mf = 0; mf < 2; ++mf) {
                bf16x8 a = ld8(&x1l[mf][c][lane * 8]);
                acc[mf] = mfma16(a, b, acc[mf]);
            }
        }
        for (int c = 0; c < 8; ++c) {        // h part (k 256..511)
            bf16x8 b = ld8(wmp + (t * 16 + 8 + c) * 512 + lane * 8);
            #pragma unroll
            for (int mf = 0; mf < 2; ++mf) {
                bf16x8 a = ld8(hbp + (tG[mf] * 8 + c) * 512 + lane * 8);
                acc[mf] = mfma16(a, b, acc[mf]);
            }
        }
        float bias = mb[col];
        #pragma unroll
        for (int mf = 0; mf < 2; ++mf) if (val[mf])
            #pragma unroll
            for (int r = 0; r < 4; ++r) {
                int row = m32 * 32 + mf * 16 + lq * 4 + r;
                Mn[row * MSGD + col] = f2bf(acc[mf][r] + bias);
            }
    }
}

// one wave per node: gather Mn rows, mean, write packed C row. 8-deep MLP unroll.
__global__ __launch_bounds__(256) void aggregate_kernel(
    const int* __restrict__ off, const int* __restrict__ deg,
    const int* __restrict__ bucket, const unsigned short* __restrict__ Mn,
    unsigned short* __restrict__ Cp)
{
    const int wave = threadIdx.x >> 6;
    const int lane = threadIdx.x & 63;
    const int node = blockIdx.x * 4 + wave;
    if (node >= N_NODES) return;
    const int o = off[node], dg = deg[node];
    float s0 = 0.f, s1 = 0.f;
    const unsigned int* mn = (const unsigned int*)Mn;
    int j = 0;
    for (; j + 8 <= dg; j += 8) {
        int ix[8];
        #pragma unroll
        for (int u = 0; u < 8; ++u) ix[u] = bucket[o + j + u];
        unsigned int pk[8];
        #pragma unroll
        for (int u = 0; u < 8; ++u) pk[u] = mn[ix[u] * 64 + lane];
        #pragma unroll
        for (int u = 0; u < 8; ++u) {
            s0 += bf2f((unsigned short)(pk[u] & 0xffffu));
            s1 += bf2f((unsigned short)(pk[u] >> 16));
        }
    }
    for (; j < dg; ++j) {
        int sidx = bucket[o + j];
        unsigned int pk = mn[sidx * 64 + lane];
        s0 += bf2f((unsigned short)(pk & 0xffffu));
        s1 += bf2f((unsigned short)(pk >> 16));
    }
    float invc = 1.0f / fmaxf((float)dg, 1.0f);
    unsigned int outpk = ((unsigned int)f2bf(s1 * invc) << 16) | (unsigned int)f2bf(s0 * invc);
    *(unsigned int*)(Cp + packIdx(node, 2 * lane, 4)) = outpk;
}

// GRU gates + h_new. R6 body exactly (fp32 h blend). 1252 blocks.
__global__ __launch_bounds__(256) void gru_kernel(
    const unsigned short* __restrict__ Xp, const unsigned short* __restrict__ Cp,
    const unsigned short* __restrict__ hbp, const float* __restrict__ h,
    const unsigned short* __restrict__ wgp,
    const float* __restrict__ bih, const float* __restrict__ bhh,
    unsigned short* __restrict__ Hnp, float* __restrict__ out)
{
    const int w = blockIdx.x * 4 + (threadIdx.x >> 6);
    const int lane = threadIdx.x & 63, lr = lane & 15, lq = lane >> 4;
    const int m64 = w >> 4, t = w & 15;
    const int col = t * 16 + lr;
    int tA[4]; bool val[4];
    #pragma unroll
    for (int mf = 0; mf < 4; ++mf) { int tl = m64 * 4 + mf; val[mf] = tl < 1250; tA[mf] = val[mf] ? tl : 1249; }

    f32x4 ar[4]  = {{0,0,0,0},{0,0,0,0},{0,0,0,0},{0,0,0,0}};
    f32x4 az[4]  = {{0,0,0,0},{0,0,0,0},{0,0,0,0},{0,0,0,0}};
    f32x4 ani[4] = {{0,0,0,0},{0,0,0,0},{0,0,0,0},{0,0,0,0}};
    f32x4 anh[4] = {{0,0,0,0},{0,0,0,0},{0,0,0,0},{0,0,0,0}};

    const unsigned short* wr = wgp + 0 * GATE_STRIDE + t * 20 * 512 + lane * 8;
    const unsigned short* wz = wgp + 1 * GATE_STRIDE + t * 20 * 512 + lane * 8;
    const unsigned short* wn = wgp + 2 * GATE_STRIDE + t * 20 * 512 + lane * 8;

    for (int c = 0; c < 8; ++c) {        // X part
        bf16x8 br = ld8(wr + c * 512);
        bf16x8 bz = ld8(wz + c * 512);
        bf16x8 bn = ld8(wn + c * 512);
        #pragma unroll
        for (int mf = 0; mf < 4; ++mf) {
            bf16x8 a = ld8(Xp + (tA[mf] * 8 + c) * 512 + lane * 8);
            ar[mf]  = mfma16(a, br, ar[mf]);
            az[mf]  = mfma16(a, bz, az[mf]);
            ani[mf] = mfma16(a, bn, ani[mf]);
        }
    }
    for (int c = 0; c < 4; ++c) {        // C part
        bf16x8 br = ld8(wr + (8 + c) * 512);
        bf16x8 bz = ld8(wz + (8 + c) * 512);
        bf16x8 bn = ld8(wn + (8 + c) * 512);
        #pragma unroll
        for (int mf = 0; mf < 4; ++mf) {
            bf16x8 a = ld8(Cp + (tA[mf] * 4 + c) * 512 + lane * 8);
            ar[mf]  = mfma16(a, br, ar[mf]);
            az[mf]  = mfma16(a, bz, az[mf]);
            ani[mf] = mfma16(a, bn, ani[mf]);
        }
    }
    for (int c = 0; c < 8; ++c) {        // h part; n-gate separate accumulator
        bf16x8 br = ld8(wr + (12 + c) * 512);
        bf16x8 bz = ld8(wz + (12 + c) * 512);
        bf16x8 bn = ld8(wn + (12 + c) * 512);
        #pragma unroll
        for (int mf = 0; mf < 4; ++mf) {
            bf16x8 a = ld8(hbp + (tA[mf] * 8 + c) * 512 + lane * 8);
            ar[mf]  = mfma16(a, br, ar[mf]);
            az[mf]  = mfma16(a, bz, az[mf]);
            anh[mf] = mfma16(a, bn, anh[mf]);
        }
    }

    const float bir = bih[col] + bhh[col];
    const float biz = bih[256 + col] + bhh[256 + col];
    const float bin = bih[512 + col];
    const float bhn = bhh[512 + col];
    #pragma unroll
    for (int mf = 0; mf < 4; ++mf) if (val[mf])
        #pragma unroll
        for (int r = 0; r < 4; ++r) {
            int row = m64 * 64 + mf * 16 + lq * 4 + r;
            float rg = sigmoidf_(ar[mf][r] + bir);
            float zg = sigmoidf_(az[mf][r] + biz);
            float ng = tanhf_(ani[mf][r] + bin + rg * (anh[mf][r] + bhn));
            float ho = h[row * HDIM + col];
            float hn = (1.0f - zg) * ng + zg * ho;
            out[HN_OFF + row * HDIM + col] = hn;
            Hnp[packIdxEp(tA[mf], lq * 4 + r, t, lr, 8)] = f2bf(hn);
        }
}

// q = h_new @ out_W + out_b. one wave per 16-row tile.
__global__ __launch_bounds__(256) void q_kernel(
    const unsigned short* __restrict__ Hnp, const unsigned short* __restrict__ wop,
    const float* __restrict__ ob, float* __restrict__ out)
{
    int w = blockIdx.x * 4 + (threadIdx.x >> 6);
    if (w >= 1250) w = 1249;
    const int lane = threadIdx.x & 63, lr = lane & 15, lq = lane >> 4;
    f32x4 acc = {0.f, 0.f, 0.f, 0.f};
    for (int c = 0; c < 8; ++c) {
        bf16x8 a = ld8(Hnp + (w * 8 + c) * 512 + lane * 8);
        bf16x8 b = ld8(wop + c * 512 + lane * 8);
        acc = mfma16(a, b, acc);
    }
    float bias = ob[lr];
    #pragma unroll
    for (int r = 0; r < 4; ++r)
        out[Q_OFF + (w * 16 + lq * 4 + r) * ADIM + lr] = acc[r] + bias;
}

extern "C" void kernel_launch(void* const* d_in, const int* in_sizes, int n_in,
                              void* d_out, int out_size, void* d_ws, size_t ws_size,
                              hipStream_t stream) {
    const float* feat = (const float*)d_in[0];
    const float* h    = (const float*)d_in[1];
    const int* src    = (const int*)d_in[2];
    const int* dst    = (const int*)d_in[3];
    const float* w0   = (const float*)d_in[4];
    const float* b0   = (const float*)d_in[5];
    const float* w1   = (const float*)d_in[6];
    const float* b1   = (const float*)d_in[7];
    const float* wm   = (const float*)d_in[8];
    const float* mb   = (const float*)d_in[9];
    const float* wih  = (const float*)d_in[10];
    const float* whh  = (const float*)d_in[11];
    const float* bih  = (const float*)d_in[12];
    const float* bhh  = (const float*)d_in[13];
    const float* wo   = (const float*)d_in[14];
    const float* ob   = (const float*)d_in[15];

    char* ws = (char*)d_ws;
    unsigned short* w0p   = (unsigned short*)(ws + WS_W0P);
    unsigned short* w1p   = (unsigned short*)(ws + WS_W1P);
    unsigned short* wmp   = (unsigned short*)(ws + WS_WMP);
    unsigned short* wgp   = (unsigned short*)(ws + WS_WGP);
    unsigned short* wop   = (unsigned short*)(ws + WS_WOP);
    unsigned short* featp = (unsigned short*)(ws + WS_FEATP);
    unsigned short* hbp   = (unsigned short*)(ws + WS_HBP);
    unsigned short* Xp    = (unsigned short*)(ws + WS_XP);
    unsigned short* Mn    = (unsigned short*)(ws + WS_MN);
    unsigned short* Cp    = (unsigned short*)(ws + WS_CP);
    unsigned short* Hnp   = (unsigned short*)(ws + WS_HNP);
    int* deg              = (int*)(ws + WS_DEG);
    int* off              = (int*)(ws + WS_OFF);
    int* cur              = (int*)(ws + WS_CUR);
    int* bucket           = (int*)(ws + WS_BUCKET);
    float* out            = (float*)d_out;

    hipMemsetAsync(deg, 0, N_NODES * sizeof(int), stream);
    hipLaunchKernelGGL(setup_kernel, dim3(1280), dim3(256), 0, stream,
                       feat, h, w0, w1, wm, wih, whh, wo, dst,
                       featp, hbp, w0p, w1p, wmp, wgp, wop, deg);
    hipLaunchKernelGGL(scan_kernel, dim3(1), dim3(1024), 0, stream, deg, off, cur);
    hipLaunchKernelGGL(scatter_idx, dim3((N_EDGES + 255) / 256), dim3(256), 0, stream, src, dst, cur, bucket);
    hipLaunchKernelGGL(enc_fused_kernel, dim3(626), dim3(256), 0, stream,
                       featp, hbp, w0p, b0, w1p, b1, wmp, mb, Xp, Mn);
    hipLaunchKernelGGL(aggregate_kernel, dim3((N_NODES + 3) / 4), dim3(256), 0, stream,
                       off, deg, bucket, Mn, Cp);
    hipLaunchKernelGGL(gru_kernel, dim3(1252), dim3(256), 0, stream,
                       Xp, Cp, hbp, h, wgp, bih, bhh, Hnp, out);
    hipLaunchKernelGGL(q_kernel, dim3(313), dim3(256), 0, stream, Hnp, wop, ob, out);
}

// Round 12
// 290.494 us; speedup vs baseline: 1.2017x; 1.0463x over previous
//
#include <hip/hip_runtime.h>

#define N_NODES 20000
#define N_EDGES 640000
#define OBS 64
#define HDIM 256
#define MSGD 128
#define ADIM 16
#define Q_OFF 0
#define HN_OFF (N_NODES * ADIM)   // 320000

typedef __bf16 bf16x8 __attribute__((ext_vector_type(8)));
typedef float  f32x4  __attribute__((ext_vector_type(4)));

__device__ __forceinline__ unsigned short f2bf(float f) {
    union { float f; unsigned int i; } v; v.f = f;
    unsigned int i = v.i;
    return (unsigned short)((i + 0x7fffu + ((i >> 16) & 1u)) >> 16);
}
__device__ __forceinline__ float bf2f(unsigned short u) {
    union { unsigned int i; float f; } v; v.i = ((unsigned int)u) << 16; return v.f;
}
__device__ __forceinline__ bf16x8 ld8(const unsigned short* p) {
    bf16x8 r;
    __builtin_memcpy(&r, __builtin_assume_aligned(p, 16), 16);
    return r;
}
__device__ __forceinline__ f32x4 mfma16(bf16x8 a, bf16x8 b, f32x4 c) {
    return __builtin_amdgcn_mfma_f32_16x16x32_bf16(a, b, c, 0, 0, 0);
}
__device__ __forceinline__ float sigmoidf_(float x) { return 1.0f / (1.0f + __expf(-x)); }
__device__ __forceinline__ float tanhf_(float x) { return 2.0f / (1.0f + __expf(-2.0f * x)) - 1.0f; }

// fragment-packed layout: element (row,k) of a K-major matrix, Kc=K/32:
__device__ __forceinline__ int packIdx(int row, int k, int Kc) {
    return ((row >> 4) * Kc + (k >> 5)) * 512 + (((k >> 3) & 3) * 16 + (row & 15)) * 8 + (k & 7);
}
__device__ __forceinline__ int packIdxEp(int tile, int rlow, int t, int lr, int Kc) {
    return (tile * Kc + (t >> 1)) * 512 + (((t & 1) * 2 + (lr >> 3)) * 16 + rlow) * 8 + (lr & 7);
}
// block-local LDS variant (tile folded out): chunk = t>>1
__device__ __forceinline__ int packIdxLoc(int rlow, int t, int lr) {
    return (t >> 1) * 512 + (((t & 1) * 2 + (lr >> 3)) * 16 + rlow) * 8 + (lr & 7);
}

// ---------------- ws layout (bytes) ----------------
#define WS_W0P    0u
#define WS_W1P    32768u
#define WS_WMP    163840u
#define WS_WGP    294912u
#define WS_WOP    1277952u
#define WS_FEATP  1286144u
#define WS_HBP    3846144u
#define WS_XP     24326144u
#define WS_MN     34566144u
#define WS_CP     39686144u
#define WS_HNP    44806144u
#define WS_DEG    55046144u
#define WS_OFF    55126144u
#define WS_CUR    55206144u
#define WS_BUCKET 55286144u   // 640000 int (end 57846144)

#define GATE_STRIDE 163840

// fused setup: feat/h -> packed bf16, weight packing, dst histogram.
__global__ __launch_bounds__(256) void setup_kernel(
    const float* __restrict__ feat, const float* __restrict__ h,
    const float* __restrict__ w0, const float* __restrict__ w1, const float* __restrict__ wm,
    const float* __restrict__ wih, const float* __restrict__ whh, const float* __restrict__ wo,
    const int* __restrict__ dst,
    unsigned short* __restrict__ featp, unsigned short* __restrict__ hbp,
    unsigned short* __restrict__ w0p, unsigned short* __restrict__ w1p,
    unsigned short* __restrict__ wmp, unsigned short* __restrict__ wgp,
    unsigned short* __restrict__ wop, int* __restrict__ deg)
{
    int tid = blockIdx.x * 256 + threadIdx.x;
    int np = gridDim.x * 256;
    for (int ch = tid; ch < N_NODES * OBS / 8; ch += np) {
        int row = ch >> 3, k = (ch & 7) * 8;
        const float4* p = (const float4*)(feat + row * OBS + k);
        float4 a = p[0], b = p[1];
        union { unsigned short u[8]; uint4 v; } r;
        r.u[0]=f2bf(a.x); r.u[1]=f2bf(a.y); r.u[2]=f2bf(a.z); r.u[3]=f2bf(a.w);
        r.u[4]=f2bf(b.x); r.u[5]=f2bf(b.y); r.u[6]=f2bf(b.z); r.u[7]=f2bf(b.w);
        *(uint4*)(featp + packIdx(row, k, 2)) = r.v;
    }
    for (int ch = tid; ch < N_NODES * HDIM / 8; ch += np) {
        int row = ch >> 5, k = (ch & 31) * 8;
        const float4* p = (const float4*)(h + row * HDIM + k);
        float4 a = p[0], b = p[1];
        union { unsigned short u[8]; uint4 v; } r;
        r.u[0]=f2bf(a.x); r.u[1]=f2bf(a.y); r.u[2]=f2bf(a.z); r.u[3]=f2bf(a.w);
        r.u[4]=f2bf(b.x); r.u[5]=f2bf(b.y); r.u[6]=f2bf(b.z); r.u[7]=f2bf(b.w);
        *(uint4*)(hbp + packIdx(row, k, 8)) = r.v;
    }
    for (int i = tid; i < 64 * 256; i += np)  { int k = i >> 8, n = i & 255; w0p[packIdx(n, k, 2)]  = f2bf(w0[i]); }
    for (int i = tid; i < 256 * 256; i += np) { int k = i >> 8, n = i & 255; w1p[packIdx(n, k, 8)]  = f2bf(w1[i]); }
    for (int i = tid; i < 512 * 128; i += np) { int k = i >> 7, n = i & 127; wmp[packIdx(n, k, 16)] = f2bf(wm[i]); }
    for (int i = tid; i < 384 * 768; i += np) {
        int k = i / 768, c3 = i % 768;
        wgp[(c3 >> 8) * GATE_STRIDE + packIdx(c3 & 255, k, 20)] = f2bf(wih[i]);
    }
    for (int i = tid; i < 256 * 768; i += np) {
        int k = i / 768, c3 = i % 768;
        wgp[(c3 >> 8) * GATE_STRIDE + packIdx(c3 & 255, 384 + k, 20)] = f2bf(whh[i]);
    }
    for (int i = tid; i < 256 * 16; i += np)  { int k = i >> 4, n = i & 15; wop[packIdx(n, k, 8)] = f2bf(wo[i]); }
    for (int i = tid; i < N_EDGES; i += np) atomicAdd(&deg[dst[i]], 1);
}

__global__ __launch_bounds__(1024) void scan_kernel(const int* __restrict__ deg,
                                                    int* __restrict__ off, int* __restrict__ cur) {
    __shared__ int part[1024];
    const int t = threadIdx.x;
    const int base = t * 20;
    int s = 0;
    #pragma unroll
    for (int i = 0; i < 20; ++i) { int idx = base + i; if (idx < N_NODES) s += deg[idx]; }
    part[t] = s;
    __syncthreads();
    int acc = s;
    for (int d = 1; d < 1024; d <<= 1) {
        int v = (t >= d) ? part[t - d] : 0;
        __syncthreads();
        acc += v; part[t] = acc;
        __syncthreads();
    }
    int run = acc - s;
    for (int i = 0; i < 20; ++i) {
        int idx = base + i;
        if (idx < N_NODES) { off[idx] = run; cur[idx] = run; run += deg[idx]; }
    }
}

__global__ __launch_bounds__(256) void scatter_idx(const int* __restrict__ src, const int* __restrict__ dst,
                                                   int* __restrict__ cur, int* __restrict__ bucket) {
    int i = blockIdx.x * 256 + threadIdx.x;
    if (i < N_EDGES) {
        int d = dst[i];
        int pos = atomicAdd(&cur[d], 1);
        bucket[pos] = src[i];
    }
}

// fused encoder: enc0 -> enc1 -> msg. One block = 32-row slab (2 tiles);
// X0 and X live in LDS; X also written packed to global for gru. grid 626.
__global__ __launch_bounds__(256) void enc_fused_kernel(
    const unsigned short* __restrict__ featp, const unsigned short* __restrict__ hbp,
    const unsigned short* __restrict__ w0p, const float* __restrict__ b0,
    const unsigned short* __restrict__ w1p, const float* __restrict__ b1,
    const unsigned short* __restrict__ wmp, const float* __restrict__ mb,
    unsigned short* __restrict__ Xp, unsigned short* __restrict__ Mn)
{
    const int wave = threadIdx.x >> 6;
    const int lane = threadIdx.x & 63, lr = lane & 15, lq = lane >> 4;
    const int m32 = blockIdx.x;          // 0..625
    int tG[2]; bool val[2];
    #pragma unroll
    for (int mf = 0; mf < 2; ++mf) { int tl = m32 * 2 + mf; val[mf] = tl < 1250; tG[mf] = val[mf] ? tl : 1249; }

    __shared__ __align__(16) unsigned short x0l[2][8][512];  // 16 KB
    __shared__ __align__(16) unsigned short x1l[2][8][512];  // 16 KB

    // ---- Stage A: X0 = relu(feat @ W0 + b0) -> LDS ----
    for (int i = 0; i < 4; ++i) {
        const int t = wave * 4 + i;
        f32x4 acc[2] = {{0,0,0,0},{0,0,0,0}};
        for (int c = 0; c < 2; ++c) {
            bf16x8 b = ld8(w0p + (t * 2 + c) * 512 + lane * 8);
            #pragma unroll
            for (int mf = 0; mf < 2; ++mf) {
                bf16x8 a = ld8(featp + (tG[mf] * 2 + c) * 512 + lane * 8);
                acc[mf] = mfma16(a, b, acc[mf]);
            }
        }
        float bias = b0[t * 16 + lr];
        #pragma unroll
        for (int mf = 0; mf < 2; ++mf)
            #pragma unroll
            for (int r = 0; r < 4; ++r)
                (&x0l[mf][0][0])[packIdxLoc(lq * 4 + r, t, lr)] = f2bf(fmaxf(acc[mf][r] + bias, 0.f));
    }
    __syncthreads();
    // ---- Stage B: X = relu(X0 @ W1 + b1) -> LDS + packed global ----
    for (int i = 0; i < 4; ++i) {
        const int t = wave * 4 + i;
        f32x4 acc[2] = {{0,0,0,0},{0,0,0,0}};
        for (int c = 0; c < 8; ++c) {
            bf16x8 b = ld8(w1p + (t * 8 + c) * 512 + lane * 8);
            #pragma unroll
            for (int mf = 0; mf < 2; ++mf) {
                bf16x8 a = ld8(&x0l[mf][c][lane * 8]);
                acc[mf] = mfma16(a, b, acc[mf]);
            }
        }
        float bias = b1[t * 16 + lr];
        #pragma unroll
        for (int mf = 0; mf < 2; ++mf)
            #pragma unroll
            for (int r = 0; r < 4; ++r) {
                unsigned short xb = f2bf(fmaxf(acc[mf][r] + bias, 0.f));
                (&x1l[mf][0][0])[packIdxLoc(lq * 4 + r, t, lr)] = xb;
                if (val[mf]) Xp[packIdxEp(tG[mf], lq * 4 + r, t, lr, 8)] = xb;
            }
    }
    __syncthreads();
    // ---- Stage C: Mnode = X @ Wx + h @ Wh + mb -> row-major global ----
    for (int i = 0; i < 2; ++i) {
        const int t = wave * 2 + i;          // 0..7
        const int col = t * 16 + lr;
        f32x4 acc[2] = {{0,0,0,0},{0,0,0,0}};
        for (int c = 0; c < 8; ++c) {        // X part, A from LDS
            bf16x8 b = ld8(wmp + (t * 16 + c) * 512 + lane * 8);
            #pragma unroll
            for (int mf = 0; mf < 2; ++mf) {
                bf16x8 a = ld8(&x1l[mf][c][lane * 8]);
                acc[mf] = mfma16(a, b, acc[mf]);
            }
        }
        for (int c = 0; c < 8; ++c) {        // h part
            bf16x8 b = ld8(wmp + (t * 16 + 8 + c) * 512 + lane * 8);
            #pragma unroll
            for (int mf = 0; mf < 2; ++mf) {
                bf16x8 a = ld8(hbp + (tG[mf] * 8 + c) * 512 + lane * 8);
                acc[mf] = mfma16(a, b, acc[mf]);
            }
        }
        float bias = mb[col];
        #pragma unroll
        for (int mf = 0; mf < 2; ++mf) if (val[mf])
            #pragma unroll
            for (int r = 0; r < 4; ++r) {
                int row = m32 * 32 + mf * 16 + lq * 4 + r;
                Mn[row * MSGD + col] = f2bf(acc[mf][r] + bias);
            }
    }
}

// one wave per node: gather Mn rows, mean, write packed C row. 8-deep MLP unroll.
__global__ __launch_bounds__(256) void aggregate_kernel(
    const int* __restrict__ off, const int* __restrict__ deg,
    const int* __restrict__ bucket, const unsigned short* __restrict__ Mn,
    unsigned short* __restrict__ Cp)
{
    const int wave = threadIdx.x >> 6;
    const int lane = threadIdx.x & 63;
    const int node = blockIdx.x * 4 + wave;
    if (node >= N_NODES) return;
    const int o = off[node], dg = deg[node];
    float s0 = 0.f, s1 = 0.f;
    const unsigned int* mn = (const unsigned int*)Mn;
    int j = 0;
    for (; j + 8 <= dg; j += 8) {
        int ix[8];
        #pragma unroll
        for (int u = 0; u < 8; ++u) ix[u] = bucket[o + j + u];
        unsigned int pk[8];
        #pragma unroll
        for (int u = 0; u < 8; ++u) pk[u] = mn[ix[u] * 64 + lane];
        #pragma unroll
        for (int u = 0; u < 8; ++u) {
            s0 += bf2f((unsigned short)(pk[u] & 0xffffu));
            s1 += bf2f((unsigned short)(pk[u] >> 16));
        }
    }
    for (; j < dg; ++j) {
        int sidx = bucket[o + j];
        unsigned int pk = mn[sidx * 64 + lane];
        s0 += bf2f((unsigned short)(pk & 0xffffu));
        s1 += bf2f((unsigned short)(pk >> 16));
    }
    float invc = 1.0f / fmaxf((float)dg, 1.0f);
    unsigned int outpk = ((unsigned int)f2bf(s1 * invc) << 16) | (unsigned int)f2bf(s0 * invc);
    *(unsigned int*)(Cp + packIdx(node, 2 * lane, 4)) = outpk;
}

// GRU gates + h_new. M=32 per wave (2 mf) for 2x wave count / occupancy.
// K=640 = [X 256 | C 128 | h 256]. grid 2504 blocks (10016 waves).
__global__ __launch_bounds__(256) void gru_kernel(
    const unsigned short* __restrict__ Xp, const unsigned short* __restrict__ Cp,
    const unsigned short* __restrict__ hbp, const float* __restrict__ h,
    const unsigned short* __restrict__ wgp,
    const float* __restrict__ bih, const float* __restrict__ bhh,
    unsigned short* __restrict__ Hnp, float* __restrict__ out)
{
    const int w = blockIdx.x * 4 + (threadIdx.x >> 6);
    const int lane = threadIdx.x & 63, lr = lane & 15, lq = lane >> 4;
    const int m32 = w >> 4, t = w & 15;
    const int col = t * 16 + lr;
    int tA[2]; bool val[2];
    #pragma unroll
    for (int mf = 0; mf < 2; ++mf) { int tl = m32 * 2 + mf; val[mf] = tl < 1250; tA[mf] = val[mf] ? tl : 1249; }

    f32x4 ar[2]  = {{0,0,0,0},{0,0,0,0}};
    f32x4 az[2]  = {{0,0,0,0},{0,0,0,0}};
    f32x4 ani[2] = {{0,0,0,0},{0,0,0,0}};
    f32x4 anh[2] = {{0,0,0,0},{0,0,0,0}};

    const unsigned short* wr = wgp + 0 * GATE_STRIDE + t * 20 * 512 + lane * 8;
    const unsigned short* wz = wgp + 1 * GATE_STRIDE + t * 20 * 512 + lane * 8;
    const unsigned short* wn = wgp + 2 * GATE_STRIDE + t * 20 * 512 + lane * 8;

    for (int c = 0; c < 8; ++c) {        // X part
        bf16x8 br = ld8(wr + c * 512);
        bf16x8 bz = ld8(wz + c * 512);
        bf16x8 bn = ld8(wn + c * 512);
        #pragma unroll
        for (int mf = 0; mf < 2; ++mf) {
            bf16x8 a = ld8(Xp + (tA[mf] * 8 + c) * 512 + lane * 8);
            ar[mf]  = mfma16(a, br, ar[mf]);
            az[mf]  = mfma16(a, bz, az[mf]);
            ani[mf] = mfma16(a, bn, ani[mf]);
        }
    }
    for (int c = 0; c < 4; ++c) {        // C part
        bf16x8 br = ld8(wr + (8 + c) * 512);
        bf16x8 bz = ld8(wz + (8 + c) * 512);
        bf16x8 bn = ld8(wn + (8 + c) * 512);
        #pragma unroll
        for (int mf = 0; mf < 2; ++mf) {
            bf16x8 a = ld8(Cp + (tA[mf] * 4 + c) * 512 + lane * 8);
            ar[mf]  = mfma16(a, br, ar[mf]);
            az[mf]  = mfma16(a, bz, az[mf]);
            ani[mf] = mfma16(a, bn, ani[mf]);
        }
    }
    for (int c = 0; c < 8; ++c) {        // h part; n-gate separate accumulator
        bf16x8 br = ld8(wr + (12 + c) * 512);
        bf16x8 bz = ld8(wz + (12 + c) * 512);
        bf16x8 bn = ld8(wn + (12 + c) * 512);
        #pragma unroll
        for (int mf = 0; mf < 2; ++mf) {
            bf16x8 a = ld8(hbp + (tA[mf] * 8 + c) * 512 + lane * 8);
            ar[mf]  = mfma16(a, br, ar[mf]);
            az[mf]  = mfma16(a, bz, az[mf]);
            anh[mf] = mfma16(a, bn, anh[mf]);
        }
    }

    const float bir = bih[col] + bhh[col];
    const float biz = bih[256 + col] + bhh[256 + col];
    const float bin = bih[512 + col];
    const float bhn = bhh[512 + col];
    #pragma unroll
    for (int mf = 0; mf < 2; ++mf) if (val[mf])
        #pragma unroll
        for (int r = 0; r < 4; ++r) {
            int row = m32 * 32 + mf * 16 + lq * 4 + r;
            float rg = sigmoidf_(ar[mf][r] + bir);
            float zg = sigmoidf_(az[mf][r] + biz);
            float ng = tanhf_(ani[mf][r] + bin + rg * (anh[mf][r] + bhn));
            float ho = h[row * HDIM + col];
            float hn = (1.0f - zg) * ng + zg * ho;
            out[HN_OFF + row * HDIM + col] = hn;
            Hnp[packIdxEp(tA[mf], lq * 4 + r, t, lr, 8)] = f2bf(hn);
        }
}

// q = h_new @ out_W + out_b. one wave per 16-row tile.
__global__ __launch_bounds__(256) void q_kernel(
    const unsigned short* __restrict__ Hnp, const unsigned short* __restrict__ wop,
    const float* __restrict__ ob, float* __restrict__ out)
{
    int w = blockIdx.x * 4 + (threadIdx.x >> 6);
    if (w >= 1250) w = 1249;
    const int lane = threadIdx.x & 63, lr = lane & 15, lq = lane >> 4;
    f32x4 acc = {0.f, 0.f, 0.f, 0.f};
    for (int c = 0; c < 8; ++c) {
        bf16x8 a = ld8(Hnp + (w * 8 + c) * 512 + lane * 8);
        bf16x8 b = ld8(wop + c * 512 + lane * 8);
        acc = mfma16(a, b, acc);
    }
    float bias = ob[lr];
    #pragma unroll
    for (int r = 0; r < 4; ++r)
        out[Q_OFF + (w * 16 + lq * 4 + r) * ADIM + lr] = acc[r] + bias;
}

extern "C" void kernel_launch(void* const* d_in, const int* in_sizes, int n_in,
                              void* d_out, int out_size, void* d_ws, size_t ws_size,
                              hipStream_t stream) {
    const float* feat = (const float*)d_in[0];
    const float* h    = (const float*)d_in[1];
    const int* src    = (const int*)d_in[2];
    const int* dst    = (const int*)d_in[3];
    const float* w0   = (const float*)d_in[4];
    const float* b0   = (const float*)d_in[5];
    const float* w1   = (const float*)d_in[6];
    const float* b1   = (const float*)d_in[7];
    const float* wm   = (const float*)d_in[8];
    const float* mb   = (const float*)d_in[9];
    const float* wih  = (const float*)d_in[10];
    const float* whh  = (const float*)d_in[11];
    const float* bih  = (const float*)d_in[12];
    const float* bhh  = (const float*)d_in[13];
    const float* wo   = (const float*)d_in[14];
    const float* ob   = (const float*)d_in[15];

    char* ws = (char*)d_ws;
    unsigned short* w0p   = (unsigned short*)(ws + WS_W0P);
    unsigned short* w1p   = (unsigned short*)(ws + WS_W1P);
    unsigned short* wmp   = (unsigned short*)(ws + WS_WMP);
    unsigned short* wgp   = (unsigned short*)(ws + WS_WGP);
    unsigned short* wop   = (unsigned short*)(ws + WS_WOP);
    unsigned short* featp = (unsigned short*)(ws + WS_FEATP);
    unsigned short* hbp   = (unsigned short*)(ws + WS_HBP);
    unsigned short* Xp    = (unsigned short*)(ws + WS_XP);
    unsigned short* Mn    = (unsigned short*)(ws + WS_MN);
    unsigned short* Cp    = (unsigned short*)(ws + WS_CP);
    unsigned short* Hnp   = (unsigned short*)(ws + WS_HNP);
    int* deg              = (int*)(ws + WS_DEG);
    int* off              = (int*)(ws + WS_OFF);
    int* cur              = (int*)(ws + WS_CUR);
    int* bucket           = (int*)(ws + WS_BUCKET);
    float* out            = (float*)d_out;

    hipMemsetAsync(deg, 0, N_NODES * sizeof(int), stream);
    hipLaunchKernelGGL(setup_kernel, dim3(1280), dim3(256), 0, stream,
                       feat, h, w0, w1, wm, wih, whh, wo, dst,
                       featp, hbp, w0p, w1p, wmp, wgp, wop, deg);
    hipLaunchKernelGGL(scan_kernel, dim3(1), dim3(1024), 0, stream, deg, off, cur);
    hipLaunchKernelGGL(scatter_idx, dim3((N_EDGES + 255) / 256), dim3(256), 0, stream, src, dst, cur, bucket);
    hipLaunchKernelGGL(enc_fused_kernel, dim3(626), dim3(256), 0, stream,
                       featp, hbp, w0p, b0, w1p, b1, wmp, mb, Xp, Mn);
    hipLaunchKernelGGL(aggregate_kernel, dim3((N_NODES + 3) / 4), dim3(256), 0, stream,
                       off, deg, bucket, Mn, Cp);
    hipLaunchKernelGGL(gru_kernel, dim3(2504), dim3(256), 0, stream,
                       Xp, Cp, hbp, h, wgp, bih, bhh, Hnp, out);
    hipLaunchKernelGGL(q_kernel, dim3(313), dim3(256), 0, stream, Hnp, wop, ob, out);
}